// Round 16
// baseline (438.135 us; speedup 1.0000x reference)
//
#include <hip/hip_runtime.h>
#include <cmath>

using f16   = _Float16;
using f16x2 = __attribute__((ext_vector_type(2))) _Float16;
using f16x4 = __attribute__((ext_vector_type(4))) _Float16;
using f16x8 = __attribute__((ext_vector_type(8))) _Float16;
using f32x4 = __attribute__((ext_vector_type(4))) float;

#define DEV __device__ __forceinline__

// ---- constants ----
constexpr int Bb  = 8;
constexpr int Nn  = 1024;
constexpr int DIM = 1024;
constexpr int Hh  = 16;
constexpr int DH  = 64;
constexpr int EQKV = 3072;   // q(1024) | k(1024) | v(1024)

DEV void async16(const f16* g, f16* l) {
  __builtin_amdgcn_global_load_lds(
      (const __attribute__((address_space(1))) void*)g,
      (__attribute__((address_space(3))) void*)l, 16, 0, 0);
}

DEV float softplusf(float x) {
  return fmaxf(x, 0.f) + __logf(1.f + __expf(-fabsf(x)));
}

// ---------------- fused prep: weight transpose + trig tables + LayerNorm ----------------
// z 0..2: transpose+cvt of w_qk/w_v/w_out; z==3: trig tables; z 4..7: LN rows.
__global__ __launch_bounds__(256) void prep_kernel(const float* __restrict__ s0,
                                                   const float* __restrict__ s1,
                                                   const float* __restrict__ s2,
                                                   f16* __restrict__ d0,
                                                   f16* __restrict__ d2,
                                                   const float* __restrict__ freqs,
                                                   const float* __restrict__ fbias,
                                                   float2* __restrict__ trigQ,
                                                   float2* __restrict__ trigK,
                                                   const float* __restrict__ x,
                                                   const float* __restrict__ gamma,
                                                   const float* __restrict__ beta,
                                                   f16* __restrict__ xn) {
  __shared__ float tile[32][33];
  __shared__ float red[8];
  int bz = blockIdx.z;
  int t = threadIdx.x;

  if (bz < 3) {
    // ---- weight transpose + fp32->fp16 ----
    const float* src; f16* dst; int cols;
    if (bz == 0)      { src = s0; dst = d0;                        cols = 2048; }
    else if (bz == 1) { src = s1; dst = d0 + (size_t)2048 * 1024;  cols = 1024; }
    else              { src = s2; dst = d2;                        cols = 1024; }
    int c0 = blockIdx.x * 32, r0 = blockIdx.y * 32;
    if (c0 >= cols) return;
    int tx = t & 31, ty = t >> 5;
#pragma unroll
    for (int j = 0; j < 32; j += 8)
      tile[ty + j][tx] = src[(size_t)(r0 + ty + j) * cols + c0 + tx];
    __syncthreads();
#pragma unroll
    for (int j = 0; j < 32; j += 8)
      dst[(size_t)(c0 + ty + j) * 1024 + r0 + tx] = (f16)tile[tx][ty + j];
  } else if (bz == 3) {
    // ---- trig tables ----
    int blk = blockIdx.y * 64 + blockIdx.x;
    if (blk >= 256) return;
    int i = blk * 256 + t;   // 0..65535
    float f = freqs[i], fb = fbias[i];
    float cq, sq, ck, sk;
    __sincosf(f, &sq, &cq);
    __sincosf(f + fb, &sk, &ck);
    trigQ[i] = make_float2(cq, sq);
    trigK[i] = make_float2(ck, sk);
  } else {
    // ---- LayerNorm (one row per block) ----
    int row = (bz - 4) * 2048 + blockIdx.y * 64 + blockIdx.x;   // 0..8191
    const float4* xr = (const float4*)(x + (size_t)row * DIM);
    float4 v = xr[t];
    float s  = v.x + v.y + v.z + v.w;
    float s2 = v.x * v.x + v.y * v.y + v.z * v.z + v.w * v.w;
#pragma unroll
    for (int off = 32; off; off >>= 1) {
      s  += __shfl_xor(s,  off, 64);
      s2 += __shfl_xor(s2, off, 64);
    }
    int wv = t >> 6, lane = t & 63;
    if (lane == 0) { red[wv] = s; red[4 + wv] = s2; }
    __syncthreads();
    s  = red[0] + red[1] + red[2] + red[3];
    s2 = red[4] + red[5] + red[6] + red[7];
    float mu  = s * (1.f / DIM);
    float var = s2 * (1.f / DIM) - mu * mu;
    float rs  = rsqrtf(var + 1e-5f);
    float4 g = ((const float4*)gamma)[t];
    float4 bb = ((const float4*)beta)[t];
    f16x4 o;
    o[0] = (f16)((v.x - mu) * rs * g.x + bb.x);
    o[1] = (f16)((v.y - mu) * rs * g.y + bb.y);
    o[2] = (f16)((v.z - mu) * rs * g.z + bb.z);
    o[3] = (f16)((v.w - mu) * rs * g.w + bb.w);
    ((f16x4*)(xn + (size_t)row * DIM))[t] = o;
  }
}

// ---------------- m97-style GEMM (out-proj): C[M,E] = A[M,K]*Bt[E,K]^T ----
template <bool FP32OUT>
__global__ __launch_bounds__(256) void gemm_bt(const f16* __restrict__ A,
                                               const f16* __restrict__ Bt,
                                               void* __restrict__ Cv,
                                               const float* __restrict__ bias,
                                               int M, int K, int E) {
  __shared__ f16 lA[128 * 32];
  __shared__ f16 lB[128 * 32];
  int tid  = threadIdx.x;
  int lane = tid & 63;
  int wv   = __builtin_amdgcn_readfirstlane(tid >> 6);
  int nbe  = E >> 7;
  const int cpx = gridDim.x >> 3;
  int bid = blockIdx.x;
  int swz = (bid & 7) * cpx + (bid >> 3);
  int bm = swz / nbe, be = swz % nbe;
  size_t m0 = (size_t)bm * 128, e0 = (size_t)be * 128;
  int wm = (wv & 1) * 64, we = (wv >> 1) * 64;
  int lm = lane & 15, q = lane >> 4;

  f32x4 acc[4][4] = {};

  int row_s[2], cg_s[2];
#pragma unroll
  for (int r = 0; r < 2; ++r) {
    int s = r * 256 + tid;
    row_s[r] = s >> 2;
    cg_s[r]  = (s & 3) ^ ((row_s[r] >> 1) & 3);
  }
  const f16* pa[4];
  const f16* pb[4];
#pragma unroll
  for (int i = 0; i < 4; ++i) {
    int ra = wm + i * 16 + lm;
    pa[i] = lA + ra * 32 + (q ^ ((ra >> 1) & 3)) * 8;
    int rb = we + i * 16 + lm;
    pb[i] = lB + rb * 32 + (q ^ ((rb >> 1) & 3)) * 8;
  }

  for (int k0 = 0; k0 < K; k0 += 32) {
#pragma unroll
    for (int r = 0; r < 2; ++r) {
      const f16* ga = A  + (m0 + row_s[r]) * K + k0 + cg_s[r] * 8;
      const f16* gb = Bt + (e0 + row_s[r]) * K + k0 + cg_s[r] * 8;
      async16(ga, lA + (r * 256 + wv * 64) * 8);
      async16(gb, lB + (r * 256 + wv * 64) * 8);
    }
    __syncthreads();
    f16x8 af[4], bf[4];
#pragma unroll
    for (int i = 0; i < 4; ++i) {
      af[i] = *(const f16x8*)pa[i];
      bf[i] = *(const f16x8*)pb[i];
    }
#pragma unroll
    for (int i = 0; i < 4; ++i)
#pragma unroll
      for (int j = 0; j < 4; ++j)
        acc[i][j] = __builtin_amdgcn_mfma_f32_16x16x32_f16(af[i], bf[j], acc[i][j], 0, 0, 0);
    __syncthreads();
  }

#pragma unroll
  for (int i = 0; i < 4; ++i) {
    size_t mbase = m0 + wm + i * 16 + q * 4;
#pragma unroll
    for (int j = 0; j < 4; ++j) {
      size_t e = e0 + we + j * 16 + lm;
#pragma unroll
      for (int g = 0; g < 4; ++g) {
        float val = acc[i][j][g];
        if (FP32OUT)
          ((float*)Cv)[(mbase + g) * (size_t)E + e] = val + bias[e];
        else
          ((f16*)Cv)[(mbase + g) * (size_t)E + e] = (f16)val;
      }
    }
  }
}

// ---------------- 128x128 QKV GEMM + fused polar/V-transpose epilogue ----------------
// Round-13/15 exact (measured best: 91.5 us, 3 blocks/CU — occupancy ladder
// closed: 1/CU=99, 3/CU=91.5, 4/CU=105 us).
__global__ __launch_bounds__(256, 4) void gemm_qkv(const f16* __restrict__ A,
                                                   const f16* __restrict__ Bt,
                                                   f16* __restrict__ Qp,
                                                   f16* __restrict__ Kp,
                                                   f16* __restrict__ Vt,
                                                   const float2* __restrict__ trigQ,
                                                   const float2* __restrict__ trigK,
                                                   int M, int K) {
  __shared__ f16 smem[17408];   // 34.8 KB: loop uses 16 KB (lA|lB); V-transpose uses [128][136]
  f16* lA = smem;
  f16* lB = smem + 4096;
  int tid  = threadIdx.x;
  int lane = tid & 63;
  int wv   = __builtin_amdgcn_readfirstlane(tid >> 6);
  const int nbe = 24;
  const int cpx = gridDim.x >> 3;     // 1536/8 = 192 (bijective XCD swizzle)
  int bid = blockIdx.x;
  int swz = (bid & 7) * cpx + (bid >> 3);
  int bm = swz / nbe, be = swz % nbe;
  size_t m0 = (size_t)bm * 128, e0 = (size_t)be * 128;
  int wm = (wv & 1) * 64, we = (wv >> 1) * 64;
  int lm = lane & 15, q = lane >> 4;

  f32x4 acc[4][4] = {};

  int row_s[2], cg_s[2];
#pragma unroll
  for (int r = 0; r < 2; ++r) {
    int s = r * 256 + tid;
    row_s[r] = s >> 2;
    cg_s[r]  = (s & 3) ^ ((row_s[r] >> 1) & 3);
  }
  const f16* pa[4];
  const f16* pb[4];
#pragma unroll
  for (int i = 0; i < 4; ++i) {
    int ra = wm + i * 16 + lm;
    pa[i] = lA + ra * 32 + (q ^ ((ra >> 1) & 3)) * 8;
    int rb = we + i * 16 + lm;
    pb[i] = lB + rb * 32 + (q ^ ((rb >> 1) & 3)) * 8;
  }

  for (int k0 = 0; k0 < K; k0 += 32) {
#pragma unroll
    for (int r = 0; r < 2; ++r) {
      const f16* ga = A  + (m0 + row_s[r]) * K + k0 + cg_s[r] * 8;
      const f16* gb = Bt + (e0 + row_s[r]) * K + k0 + cg_s[r] * 8;
      async16(ga, lA + (r * 256 + wv * 64) * 8);
      async16(gb, lB + (r * 256 + wv * 64) * 8);
    }
    __syncthreads();
    f16x8 af[4], bf[4];
#pragma unroll
    for (int i = 0; i < 4; ++i) {
      af[i] = *(const f16x8*)pa[i];
      bf[i] = *(const f16x8*)pb[i];
    }
#pragma unroll
    for (int i = 0; i < 4; ++i)
#pragma unroll
      for (int j = 0; j < 4; ++j)
        acc[i][j] = __builtin_amdgcn_mfma_f32_16x16x32_f16(af[i], bf[j], acc[i][j], 0, 0, 0);
    __syncthreads();
  }

  // ---- fused epilogue ----
  const int sec = be >> 3;   // 0=q (be 0..7), 1=k (8..15), 2=v (16..23)
  if (sec < 2) {
    f16* dst = (sec == 0) ? Qp : Kp;
    const float2* trig = (sec == 0) ? trigQ : trigK;
    const float scl = (sec == 0) ? 0.125f : 1.0f;   // DH^-0.5 folded into Q
#pragma unroll
    for (int i = 0; i < 4; ++i) {
      size_t mbase = m0 + wm + i * 16 + q * 4;
#pragma unroll
      for (int j = 0; j < 4; ++j) {
        int hd = (int)((e0 + we + j * 16 + lm) & 1023);
        int h = hd >> 6, d = hd & 63;
#pragma unroll
        for (int g = 0; g < 4; ++g) {
          size_t tok = mbase + g;
          int n = (int)(tok & 1023);
          size_t bh = (tok >> 10) * 16 + h;
          float sp = softplusf(acc[i][j][g]) * scl;
          float2 T = trig[n * 64 + d];
          f16x2 o = { (f16)(sp * T.x), (f16)(sp * T.y) };
          *(f16x2*)(dst + (bh * (size_t)Nn + n) * 128 + 2 * d) = o;
        }
      }
    }
  } else {
    // ---- V: transpose through LDS, store Vt[bh][d][n] coalesced ----
    __syncthreads();   // all waves done with lA/lB before overwrite
#pragma unroll
    for (int i = 0; i < 4; ++i) {
      int nl = wm + i * 16 + q * 4;           // local token 0..127 (+g)
#pragma unroll
      for (int j = 0; j < 4; ++j) {
        int ds = we + j * 16 + lm;            // d-slot 0..127 (2 heads x 64 d)
#pragma unroll
        for (int g = 0; g < 4; ++g)
          smem[ds * 136 + nl + g] = (f16)acc[i][j][g];
      }
    }
    __syncthreads();
    const int nbase = (int)(m0 & 1023);       // 128-token tile never crosses batch
    const size_t bh0 = (m0 >> 10) * 16 + ((e0 & 1023) >> 6);
#pragma unroll
    for (int k = 0; k < 8; ++k) {
      int c = k * 256 + tid;                  // 0..2047 flat 16B-chunk index
      int row = c >> 4, ch = c & 15;          // 16 lanes span one row's 256B
      int h = row >> 6, d = row & 63;
      f16x8 v8 = *(const f16x8*)(smem + row * 136 + ch * 8);
      *(f16x8*)(Vt + ((bh0 + h) * (size_t)64 + d) * Nn + nbase + ch * 8) = v8;
    }
  }
}

// ---------------- flash attention v6: NO LDS staging (m169 technique) ----------------
// K/V for one bh = 384 KB — L2/L3-resident (8 qt-blocks of the same bh share
// the same XCD via the swizzle).  Per-fragment LDS reuse in v5 was only ~2x,
// while costing DMA + 2 barriers/tile + 4.7M bank-conflict cycles.  Here K/V
// fragments load DIRECTLY from global (un-swizzled addresses = v5's LDS layout
// composed with its read swizzle), the ones-row rowsum tile is synthesized in
// registers (lm==0 -> 1.0), and the kernel has ZERO LDS / ZERO barriers: waves
// are fully independent, so the compiler pipelines loads across the whole kt
// loop and 4 blocks/CU (grid 1024 = one exact round) provide TLP.
__global__ __launch_bounds__(256, 4) void attn_kernel(const f16* __restrict__ Qp,
                                                      const f16* __restrict__ Kp,
                                                      const f16* __restrict__ Vt,
                                                      f16* __restrict__ attout) {
  int tid = threadIdx.x, lane = tid & 63;
  int lm = lane & 15, q = lane >> 4;
  int wv = __builtin_amdgcn_readfirstlane(tid >> 6);  // 0..3
  int bx = blockIdx.x;
  int bh = (bx & 7) | ((bx >> 6) << 3);  // XCD swizzle: same head -> same bx%8
  int qt = (bx >> 3) & 7;                // 8 q-tiles of 128 rows
  const f16* Kbase = Kp + (size_t)bh * Nn * 128;
  const f16* Vbase = Vt + (size_t)bh * 64 * Nn;

  // ---- Q frags: 32 rows/wave = 2 groups of 16 (B operand of S^T) ----
  f16x8 qf[2][4];
  {
    const f16* Qb = Qp + ((size_t)bh * Nn + qt * 128 + wv * 32) * 128;
#pragma unroll
    for (int grp = 0; grp < 2; ++grp)
#pragma unroll
      for (int ks = 0; ks < 4; ++ks)
        qf[grp][ks] = *(const f16x8*)(Qb + (size_t)(grp * 16 + lm) * 128 + ks * 32 + q * 8);
  }

  f32x4 O[2][5] = {};   // O^T per group; [.][4] row 0 = softmax denominator
  float mrow[2] = {-INFINITY, -INFINITY};
  const f16x4 vones = {(f16)1.f, (f16)1.f, (f16)1.f, (f16)1.f};
  const f16x4 vzero = {(f16)0.f, (f16)0.f, (f16)0.f, (f16)0.f};
  const f16x4 vsyn  = (lm == 0) ? vones : vzero;   // synthetic ones-row fragment

  for (int kt = 0; kt < 16; ++kt) {
    const f16* Kt = Kbase + (size_t)kt * 64 * 128;

    // ---- S^T = Kp * Qp^T (64 keys x 32 q-rows); kf direct from global ----
    f32x4 S[2][4] = {};
#pragma unroll
    for (int nt = 0; nt < 4; ++nt) {
      f16x8 kf[4];
#pragma unroll
      for (int ks = 0; ks < 4; ++ks)
        kf[ks] = *(const f16x8*)(Kt + (size_t)(nt * 16 + lm) * 128 + ks * 32 + q * 8);
#pragma unroll
      for (int ks = 0; ks < 4; ++ks) {
        S[0][nt] = __builtin_amdgcn_mfma_f32_16x16x32_f16(kf[ks], qf[0][ks], S[0][nt], 0, 0, 0);
        S[1][nt] = __builtin_amdgcn_mfma_f32_16x16x32_f16(kf[ks], qf[1][ks], S[1][nt], 0, 0, 0);
      }
    }

    // ---- online softmax per group (rowsum folded into synthetic ones-row) ----
    f16x4 pf[2][4];
#pragma unroll
    for (int grp = 0; grp < 2; ++grp) {
      float mx = -INFINITY;
#pragma unroll
      for (int nt = 0; nt < 4; ++nt)
#pragma unroll
        for (int g = 0; g < 4; ++g) mx = fmaxf(mx, S[grp][nt][g]);
      mx = fmaxf(mx, __shfl_xor(mx, 16, 64));
      mx = fmaxf(mx, __shfl_xor(mx, 32, 64));
      float mn = fmaxf(mrow[grp], mx);
      float alpha = __expf(mrow[grp] - mn);
      mrow[grp] = mn;
#pragma unroll
      for (int nt = 0; nt < 4; ++nt)
#pragma unroll
        for (int g = 0; g < 4; ++g)
          pf[grp][nt][g] = (f16)__expf(S[grp][nt][g] - mn);
#pragma unroll
      for (int nto = 0; nto < 5; ++nto)
#pragma unroll
        for (int g = 0; g < 4; ++g) O[grp][nto][g] *= alpha;
    }

    // ---- O^T += V^T * P^T ; vf direct from global (rows 0..63) ----
#pragma unroll
    for (int nto = 0; nto < 4; ++nto) {
      const f16* Vr = Vbase + (size_t)(nto * 16 + lm) * Nn + kt * 64;
#pragma unroll
      for (int nt = 0; nt < 4; ++nt) {
        f16x4 vf = *(const f16x4*)(Vr + nt * 16 + q * 4);
        O[0][nto] = __builtin_amdgcn_mfma_f32_16x16x16f16(vf, pf[0][nt], O[0][nto], 0, 0, 0);
        O[1][nto] = __builtin_amdgcn_mfma_f32_16x16x16f16(vf, pf[1][nt], O[1][nto], 0, 0, 0);
      }
    }
    // nto == 4: synthetic ones-row accumulates the softmax denominator
#pragma unroll
    for (int nt = 0; nt < 4; ++nt) {
      O[0][4] = __builtin_amdgcn_mfma_f32_16x16x16f16(vsyn, pf[0][nt], O[0][4], 0, 0, 0);
      O[1][4] = __builtin_amdgcn_mfma_f32_16x16x16f16(vsyn, pf[1][nt], O[1][4], 0, 0, 0);
    }
  }

  // ---- epilogue: l = O[grp][4][0] (d-row 64, lives in q==0 lanes), broadcast ----
  int b = bh >> 4, h = bh & 15;
#pragma unroll
  for (int grp = 0; grp < 2; ++grp) {
    float l = __shfl(O[grp][4][0], lm, 64);  // source lane lm (q==0) holds the rowsum
    float inv = 1.f / l;
    size_t token = (size_t)b * Nn + qt * 128 + wv * 32 + grp * 16 + lm;
#pragma unroll
    for (int nto = 0; nto < 4; ++nto) {
      f16x4 o4;
#pragma unroll
      for (int g = 0; g < 4; ++g) o4[g] = (f16)(O[grp][nto][g] * inv);
      *(f16x4*)(attout + token * (size_t)(Hh * DH) + h * 64 + nto * 16 + q * 4) = o4;
    }
  }
}

// ---------------- launch ----------------
extern "C" void kernel_launch(void* const* d_in, const int* in_sizes, int n_in,
                              void* d_out, int out_size, void* d_ws, size_t ws_size,
                              hipStream_t stream) {
  const float* x     = (const float*)d_in[0];
  const float* freqs = (const float*)d_in[1];
  const float* fbias = (const float*)d_in[2];
  const float* gamma = (const float*)d_in[3];
  const float* beta  = (const float*)d_in[4];
  const float* w_qk  = (const float*)d_in[5];
  const float* w_v   = (const float*)d_in[6];
  const float* w_out = (const float*)d_in[7];
  const float* b_out = (const float*)d_in[8];
  float* out = (float*)d_out;

  const size_t T = (size_t)Bb * Nn;  // 8192 tokens
  f16* WqkvT = (f16*)d_ws;                        // [3072][1024]
  f16* WoutT = WqkvT + (size_t)EQKV * DIM;        // [1024][1024]
  float2* trigQ = (float2*)(WoutT + (size_t)DIM * DIM);  // [1024*64] float2 (512 KB)
  float2* trigK = trigQ + (size_t)Nn * DH;               // [1024*64] float2 (512 KB)
  f16* Xn    = (f16*)(trigK + (size_t)Nn * DH);   // [8192][1024]
  f16* AttO  = Xn + T * DIM;                      // [8192][1024]
  f16* Qp    = AttO + T * DIM;                    // [128][1024][128]
  f16* Kp    = Qp + (size_t)128 * Nn * 128;       // [128][1024][128]
  f16* Vt    = Kp + (size_t)128 * Nn * 128;       // [128][64][1024]

  // fused prep: weight transpose (z 0-2) + trig (z 3) + LayerNorm (z 4-7)
  prep_kernel<<<dim3(64, 32, 8), 256, 0, stream>>>(
      w_qk, w_v, w_out, WqkvT, WoutT, freqs, fbias, trigQ, trigK,
      x, gamma, beta, Xn);

  // QKV projection + fused polar/V-transpose epilogue: 1536 blocks, 3/CU (r13 best)
  gemm_qkv<<<(int)(T / 128) * (EQKV / 128), 256, 0, stream>>>(
      Xn, WqkvT, Qp, Kp, Vt, trigQ, trigK, (int)T, DIM);

  // attention v6: no-LDS direct-global — 1024 blocks x 256 threads, 4/CU exact
  attn_kernel<<<Bb * Hh * (Nn / 128), 256, 0, stream>>>(Qp, Kp, Vt, AttO);

  // out-proj: 512 blocks (%8==0) with bijective XCD swizzle
  gemm_bt<true><<<(int)(T / 128) * (DIM / 128), 256, 0, stream>>>(
      AttO, WoutT, (void*)out, b_out, (int)T, DIM, DIM);
}

// Round 17
// 272.958 us; speedup vs baseline: 1.6051x; 1.6051x over previous
//
#include <hip/hip_runtime.h>
#include <cmath>

using f16   = _Float16;
using f16x2 = __attribute__((ext_vector_type(2))) _Float16;
using f16x4 = __attribute__((ext_vector_type(4))) _Float16;
using f16x8 = __attribute__((ext_vector_type(8))) _Float16;
using f32x4 = __attribute__((ext_vector_type(4))) float;

#define DEV __device__ __forceinline__

// ---- constants ----
constexpr int Bb  = 8;
constexpr int Nn  = 1024;
constexpr int DIM = 1024;
constexpr int Hh  = 16;
constexpr int DH  = 64;
constexpr int EQKV = 3072;   // q(1024) | k(1024) | v(1024)

DEV void async16(const f16* g, f16* l) {
  __builtin_amdgcn_global_load_lds(
      (const __attribute__((address_space(1))) void*)g,
      (__attribute__((address_space(3))) void*)l, 16, 0, 0);
}

DEV float softplusf(float x) {
  return fmaxf(x, 0.f) + __logf(1.f + __expf(-fabsf(x)));
}

// ---------------- fused prep: weight transpose + trig tables + LayerNorm ----------------
// z 0..2: transpose+cvt of w_qk/w_v/w_out; z==3: trig tables; z 4..7: LN rows.
__global__ __launch_bounds__(256) void prep_kernel(const float* __restrict__ s0,
                                                   const float* __restrict__ s1,
                                                   const float* __restrict__ s2,
                                                   f16* __restrict__ d0,
                                                   f16* __restrict__ d2,
                                                   const float* __restrict__ freqs,
                                                   const float* __restrict__ fbias,
                                                   float2* __restrict__ trigQ,
                                                   float2* __restrict__ trigK,
                                                   const float* __restrict__ x,
                                                   const float* __restrict__ gamma,
                                                   const float* __restrict__ beta,
                                                   f16* __restrict__ xn) {
  __shared__ float tile[32][33];
  __shared__ float red[8];
  int bz = blockIdx.z;
  int t = threadIdx.x;

  if (bz < 3) {
    // ---- weight transpose + fp32->fp16 ----
    const float* src; f16* dst; int cols;
    if (bz == 0)      { src = s0; dst = d0;                        cols = 2048; }
    else if (bz == 1) { src = s1; dst = d0 + (size_t)2048 * 1024;  cols = 1024; }
    else              { src = s2; dst = d2;                        cols = 1024; }
    int c0 = blockIdx.x * 32, r0 = blockIdx.y * 32;
    if (c0 >= cols) return;
    int tx = t & 31, ty = t >> 5;
#pragma unroll
    for (int j = 0; j < 32; j += 8)
      tile[ty + j][tx] = src[(size_t)(r0 + ty + j) * cols + c0 + tx];
    __syncthreads();
#pragma unroll
    for (int j = 0; j < 32; j += 8)
      dst[(size_t)(c0 + ty + j) * 1024 + r0 + tx] = (f16)tile[tx][ty + j];
  } else if (bz == 3) {
    // ---- trig tables ----
    int blk = blockIdx.y * 64 + blockIdx.x;
    if (blk >= 256) return;
    int i = blk * 256 + t;   // 0..65535
    float f = freqs[i], fb = fbias[i];
    float cq, sq, ck, sk;
    __sincosf(f, &sq, &cq);
    __sincosf(f + fb, &sk, &ck);
    trigQ[i] = make_float2(cq, sq);
    trigK[i] = make_float2(ck, sk);
  } else {
    // ---- LayerNorm (one row per block) ----
    int row = (bz - 4) * 2048 + blockIdx.y * 64 + blockIdx.x;   // 0..8191
    const float4* xr = (const float4*)(x + (size_t)row * DIM);
    float4 v = xr[t];
    float s  = v.x + v.y + v.z + v.w;
    float s2 = v.x * v.x + v.y * v.y + v.z * v.z + v.w * v.w;
#pragma unroll
    for (int off = 32; off; off >>= 1) {
      s  += __shfl_xor(s,  off, 64);
      s2 += __shfl_xor(s2, off, 64);
    }
    int wv = t >> 6, lane = t & 63;
    if (lane == 0) { red[wv] = s; red[4 + wv] = s2; }
    __syncthreads();
    s  = red[0] + red[1] + red[2] + red[3];
    s2 = red[4] + red[5] + red[6] + red[7];
    float mu  = s * (1.f / DIM);
    float var = s2 * (1.f / DIM) - mu * mu;
    float rs  = rsqrtf(var + 1e-5f);
    float4 g = ((const float4*)gamma)[t];
    float4 bb = ((const float4*)beta)[t];
    f16x4 o;
    o[0] = (f16)((v.x - mu) * rs * g.x + bb.x);
    o[1] = (f16)((v.y - mu) * rs * g.y + bb.y);
    o[2] = (f16)((v.z - mu) * rs * g.z + bb.z);
    o[3] = (f16)((v.w - mu) * rs * g.w + bb.w);
    ((f16x4*)(xn + (size_t)row * DIM))[t] = o;
  }
}

// ---------------- m97-style GEMM (out-proj): C[M,E] = A[M,K]*Bt[E,K]^T ----
// + bijective XCD swizzle (T1; grid 512 % 8 == 0).
template <bool FP32OUT>
__global__ __launch_bounds__(256) void gemm_bt(const f16* __restrict__ A,
                                               const f16* __restrict__ Bt,
                                               void* __restrict__ Cv,
                                               const float* __restrict__ bias,
                                               int M, int K, int E) {
  __shared__ f16 lA[128 * 32];
  __shared__ f16 lB[128 * 32];
  int tid  = threadIdx.x;
  int lane = tid & 63;
  int wv   = __builtin_amdgcn_readfirstlane(tid >> 6);
  int nbe  = E >> 7;
  const int cpx = gridDim.x >> 3;
  int bid = blockIdx.x;
  int swz = (bid & 7) * cpx + (bid >> 3);
  int bm = swz / nbe, be = swz % nbe;
  size_t m0 = (size_t)bm * 128, e0 = (size_t)be * 128;
  int wm = (wv & 1) * 64, we = (wv >> 1) * 64;
  int lm = lane & 15, q = lane >> 4;

  f32x4 acc[4][4] = {};

  int row_s[2], cg_s[2];
#pragma unroll
  for (int r = 0; r < 2; ++r) {
    int s = r * 256 + tid;
    row_s[r] = s >> 2;
    cg_s[r]  = (s & 3) ^ ((row_s[r] >> 1) & 3);
  }
  const f16* pa[4];
  const f16* pb[4];
#pragma unroll
  for (int i = 0; i < 4; ++i) {
    int ra = wm + i * 16 + lm;
    pa[i] = lA + ra * 32 + (q ^ ((ra >> 1) & 3)) * 8;
    int rb = we + i * 16 + lm;
    pb[i] = lB + rb * 32 + (q ^ ((rb >> 1) & 3)) * 8;
  }

  for (int k0 = 0; k0 < K; k0 += 32) {
#pragma unroll
    for (int r = 0; r < 2; ++r) {
      const f16* ga = A  + (m0 + row_s[r]) * K + k0 + cg_s[r] * 8;
      const f16* gb = Bt + (e0 + row_s[r]) * K + k0 + cg_s[r] * 8;
      async16(ga, lA + (r * 256 + wv * 64) * 8);
      async16(gb, lB + (r * 256 + wv * 64) * 8);
    }
    __syncthreads();
    f16x8 af[4], bf[4];
#pragma unroll
    for (int i = 0; i < 4; ++i) {
      af[i] = *(const f16x8*)pa[i];
      bf[i] = *(const f16x8*)pb[i];
    }
#pragma unroll
    for (int i = 0; i < 4; ++i)
#pragma unroll
      for (int j = 0; j < 4; ++j)
        acc[i][j] = __builtin_amdgcn_mfma_f32_16x16x32_f16(af[i], bf[j], acc[i][j], 0, 0, 0);
    __syncthreads();
  }

#pragma unroll
  for (int i = 0; i < 4; ++i) {
    size_t mbase = m0 + wm + i * 16 + q * 4;
#pragma unroll
    for (int j = 0; j < 4; ++j) {
      size_t e = e0 + we + j * 16 + lm;
#pragma unroll
      for (int g = 0; g < 4; ++g) {
        float val = acc[i][j][g];
        if (FP32OUT)
          ((float*)Cv)[(mbase + g) * (size_t)E + e] = val + bias[e];
        else
          ((f16*)Cv)[(mbase + g) * (size_t)E + e] = (f16)val;
      }
    }
  }
}

// ---------------- 128x128 QKV GEMM + fused polar/V-transpose epilogue ----------------
// Round-13/15 exact (measured best: 91.5 us, 3 blocks/CU — occupancy ladder
// closed: 1/CU=99, 3/CU=91.5, 4/CU=105 us).
__global__ __launch_bounds__(256, 4) void gemm_qkv(const f16* __restrict__ A,
                                                   const f16* __restrict__ Bt,
                                                   f16* __restrict__ Qp,
                                                   f16* __restrict__ Kp,
                                                   f16* __restrict__ Vt,
                                                   const float2* __restrict__ trigQ,
                                                   const float2* __restrict__ trigK,
                                                   int M, int K) {
  __shared__ f16 smem[17408];   // 34.8 KB: loop uses 16 KB (lA|lB); V-transpose uses [128][136]
  f16* lA = smem;
  f16* lB = smem + 4096;
  int tid  = threadIdx.x;
  int lane = tid & 63;
  int wv   = __builtin_amdgcn_readfirstlane(tid >> 6);
  const int nbe = 24;
  const int cpx = gridDim.x >> 3;     // 1536/8 = 192 (bijective XCD swizzle)
  int bid = blockIdx.x;
  int swz = (bid & 7) * cpx + (bid >> 3);
  int bm = swz / nbe, be = swz % nbe;
  size_t m0 = (size_t)bm * 128, e0 = (size_t)be * 128;
  int wm = (wv & 1) * 64, we = (wv >> 1) * 64;
  int lm = lane & 15, q = lane >> 4;

  f32x4 acc[4][4] = {};

  int row_s[2], cg_s[2];
#pragma unroll
  for (int r = 0; r < 2; ++r) {
    int s = r * 256 + tid;
    row_s[r] = s >> 2;
    cg_s[r]  = (s & 3) ^ ((row_s[r] >> 1) & 3);
  }
  const f16* pa[4];
  const f16* pb[4];
#pragma unroll
  for (int i = 0; i < 4; ++i) {
    int ra = wm + i * 16 + lm;
    pa[i] = lA + ra * 32 + (q ^ ((ra >> 1) & 3)) * 8;
    int rb = we + i * 16 + lm;
    pb[i] = lB + rb * 32 + (q ^ ((rb >> 1) & 3)) * 8;
  }

  for (int k0 = 0; k0 < K; k0 += 32) {
#pragma unroll
    for (int r = 0; r < 2; ++r) {
      const f16* ga = A  + (m0 + row_s[r]) * K + k0 + cg_s[r] * 8;
      const f16* gb = Bt + (e0 + row_s[r]) * K + k0 + cg_s[r] * 8;
      async16(ga, lA + (r * 256 + wv * 64) * 8);
      async16(gb, lB + (r * 256 + wv * 64) * 8);
    }
    __syncthreads();
    f16x8 af[4], bf[4];
#pragma unroll
    for (int i = 0; i < 4; ++i) {
      af[i] = *(const f16x8*)pa[i];
      bf[i] = *(const f16x8*)pb[i];
    }
#pragma unroll
    for (int i = 0; i < 4; ++i)
#pragma unroll
      for (int j = 0; j < 4; ++j)
        acc[i][j] = __builtin_amdgcn_mfma_f32_16x16x32_f16(af[i], bf[j], acc[i][j], 0, 0, 0);
    __syncthreads();
  }

  // ---- fused epilogue ----
  const int sec = be >> 3;   // 0=q (be 0..7), 1=k (8..15), 2=v (16..23)
  if (sec < 2) {
    f16* dst = (sec == 0) ? Qp : Kp;
    const float2* trig = (sec == 0) ? trigQ : trigK;
    const float scl = (sec == 0) ? 0.125f : 1.0f;   // DH^-0.5 folded into Q
#pragma unroll
    for (int i = 0; i < 4; ++i) {
      size_t mbase = m0 + wm + i * 16 + q * 4;
#pragma unroll
      for (int j = 0; j < 4; ++j) {
        int hd = (int)((e0 + we + j * 16 + lm) & 1023);
        int h = hd >> 6, d = hd & 63;
#pragma unroll
        for (int g = 0; g < 4; ++g) {
          size_t tok = mbase + g;
          int n = (int)(tok & 1023);
          size_t bh = (tok >> 10) * 16 + h;
          float sp = softplusf(acc[i][j][g]) * scl;
          float2 T = trig[n * 64 + d];
          f16x2 o = { (f16)(sp * T.x), (f16)(sp * T.y) };
          *(f16x2*)(dst + (bh * (size_t)Nn + n) * 128 + 2 * d) = o;
        }
      }
    }
  } else {
    // ---- V: transpose through LDS, store Vt[bh][d][n] coalesced ----
    __syncthreads();   // all waves done with lA/lB before overwrite
#pragma unroll
    for (int i = 0; i < 4; ++i) {
      int nl = wm + i * 16 + q * 4;           // local token 0..127 (+g)
#pragma unroll
      for (int j = 0; j < 4; ++j) {
        int ds = we + j * 16 + lm;            // d-slot 0..127 (2 heads x 64 d)
#pragma unroll
        for (int g = 0; g < 4; ++g)
          smem[ds * 136 + nl + g] = (f16)acc[i][j][g];
      }
    }
    __syncthreads();
    const int nbase = (int)(m0 & 1023);       // 128-token tile never crosses batch
    const size_t bh0 = (m0 >> 10) * 16 + ((e0 & 1023) >> 6);
#pragma unroll
    for (int k = 0; k < 8; ++k) {
      int c = k * 256 + tid;                  // 0..2047 flat 16B-chunk index
      int row = c >> 4, ch = c & 15;          // 16 lanes span one row's 256B
      int h = row >> 6, d = row & 63;
      f16x8 v8 = *(const f16x8*)(smem + row * 136 + ch * 8);
      *(f16x8*)(Vt + ((bh0 + h) * (size_t)64 + d) * Nn + nbase + ch * 8) = v8;
    }
  }
}

// ---------------- flash attention v5 (round-1 exact, 76.6 us) ----------------
// 256 threads / 4 waves / 128 q-rows / 1024 blocks, __syncthreads pipeline.
// Rounds 2-7 + 16 showed every modification regresses (8-wave shape, counted
// vmcnt, exp2/defer-max/cvt_pk, setprio, no-LDS direct-global) — this LDS-
// staged structure is the measured optimum for this kernel family.
constexpr int VK0 = 0;       // halfs
constexpr int VK1 = 8192;
constexpr int VV0 = 16384;   // 80*64 = 5120 halfs per buffer
constexpr int VV1 = 21504;
constexpr int VEND = 26624;

__global__ __launch_bounds__(256, 3) void attn_kernel(const f16* __restrict__ Qp,
                                                      const f16* __restrict__ Kp,
                                                      const f16* __restrict__ Vt,
                                                      f16* __restrict__ attout) {
  __shared__ f16 smem[VEND];  // 52 KB

  int tid = threadIdx.x, lane = tid & 63;
  int wv = __builtin_amdgcn_readfirstlane(tid >> 6);  // 0..3
  int lm = lane & 15, q = lane >> 4;
  int bx = blockIdx.x;
  int bh = (bx & 7) | ((bx >> 6) << 3);  // XCD swizzle: same head -> same bx%8
  int qt = (bx >> 3) & 7;                // 8 q-tiles of 128 rows
  const f16* Kbase = Kp + (size_t)bh * Nn * 128;
  const f16* Vbase = Vt + (size_t)bh * 64 * Nn;

  // ---- init V rows 64..79 (row 64 = ones, rest 0) in BOTH buffers, once ----
  {
    int idx = tid * 4;                 // 0..1020
    f16 val = (idx < 64) ? (f16)1.0f : (f16)0.0f;  // idx>>6==0 -> row 64
    f16x4 v4 = {val, val, val, val};
    *(f16x4*)(smem + VV0 + 64 * 64 + idx) = v4;
    *(f16x4*)(smem + VV1 + 64 * 64 + idx) = v4;
  }

  // ---- prologue: DMA K/V tile 0 ----
#pragma unroll
  for (int i = 0; i < 4; ++i) {
    int s = i * 256 + tid;
    int r = s >> 4, c = s & 15;
    int g = c ^ (r & 15);
    async16(Kbase + (size_t)r * 128 + g * 8, smem + VK0 + (i * 256 + wv * 64) * 8);
  }
#pragma unroll
  for (int i = 0; i < 2; ++i) {
    int s = i * 256 + tid;
    int r = s >> 3, c = s & 7;
    int g = c ^ (r & 7);
    async16(Vbase + (size_t)r * Nn + g * 8, smem + VV0 + (i * 256 + wv * 64) * 8);
  }

  // ---- Q frags: 32 rows/wave = 2 groups of 16 (B operand of S^T) ----
  f16x8 qf[2][4];
  {
    const f16* Qb = Qp + ((size_t)bh * Nn + qt * 128 + wv * 32) * 128;
#pragma unroll
    for (int grp = 0; grp < 2; ++grp)
#pragma unroll
      for (int ks = 0; ks < 4; ++ks)
        qf[grp][ks] = *(const f16x8*)(Qb + (size_t)(grp * 16 + lm) * 128 + ks * 32 + q * 8);
  }

  f32x4 O[2][5] = {};   // O^T per group; [.][4] row 0 = softmax denominator
  float mrow[2] = {-INFINITY, -INFINITY};

  for (int kt = 0; kt < 16; ++kt) {
    __syncthreads();  // tile kt ready (its DMA was issued a full compute-phase ago)

    if (kt < 15) {
      f16* nK = smem + ((kt & 1) ? VK0 : VK1);
      f16* nV = smem + ((kt & 1) ? VV0 : VV1);
#pragma unroll
      for (int i = 0; i < 4; ++i) {
        int s = i * 256 + tid;
        int r = s >> 4, c = s & 15;
        int g = c ^ (r & 15);
        async16(Kbase + (size_t)((kt + 1) * 64 + r) * 128 + g * 8, nK + (i * 256 + wv * 64) * 8);
      }
#pragma unroll
      for (int i = 0; i < 2; ++i) {
        int s = i * 256 + tid;
        int r = s >> 3, c = s & 7;
        int g = c ^ (r & 7);
        async16(Vbase + (size_t)r * Nn + (kt + 1) * 64 + g * 8, nV + (i * 256 + wv * 64) * 8);
      }
    }
    const f16* sK = smem + ((kt & 1) ? VK1 : VK0);
    const f16* sV = smem + ((kt & 1) ? VV1 : VV0);

    // ---- S^T = Kp * Qp^T (64 keys x 32 q-rows); kf loaded once per nt ----
    f32x4 S[2][4] = {};
#pragma unroll
    for (int nt = 0; nt < 4; ++nt) {
      f16x8 kf[4];
#pragma unroll
      for (int ks = 0; ks < 4; ++ks)
        kf[ks] = *(const f16x8*)(sK + (nt * 16 + lm) * 128 + (((ks * 4 + q) ^ lm) * 8));
#pragma unroll
      for (int ks = 0; ks < 4; ++ks) {
        S[0][nt] = __builtin_amdgcn_mfma_f32_16x16x32_f16(kf[ks], qf[0][ks], S[0][nt], 0, 0, 0);
        S[1][nt] = __builtin_amdgcn_mfma_f32_16x16x32_f16(kf[ks], qf[1][ks], S[1][nt], 0, 0, 0);
      }
    }

    // ---- online softmax per group (no rowsum: folded into PV ones-row) ----
    f16x4 pf[2][4];
#pragma unroll
    for (int grp = 0; grp < 2; ++grp) {
      float mx = -INFINITY;
#pragma unroll
      for (int nt = 0; nt < 4; ++nt)
#pragma unroll
        for (int g = 0; g < 4; ++g) mx = fmaxf(mx, S[grp][nt][g]);
      mx = fmaxf(mx, __shfl_xor(mx, 16, 64));
      mx = fmaxf(mx, __shfl_xor(mx, 32, 64));
      float mn = fmaxf(mrow[grp], mx);
      float alpha = __expf(mrow[grp] - mn);
      mrow[grp] = mn;
#pragma unroll
      for (int nt = 0; nt < 4; ++nt)
#pragma unroll
        for (int g = 0; g < 4; ++g)
          pf[grp][nt][g] = (f16)__expf(S[grp][nt][g] - mn);
#pragma unroll
      for (int nto = 0; nto < 5; ++nto)
#pragma unroll
        for (int g = 0; g < 4; ++g) O[grp][nto][g] *= alpha;
    }

    // ---- O^T += V^T * P^T ; vf loaded once per (nto,nt), reused by both groups ----
#pragma unroll
    for (int nto = 0; nto < 5; ++nto) {
      int r = nto * 16 + lm;
#pragma unroll
      for (int nt = 0; nt < 4; ++nt) {
        int c16 = (nt * 2 + (q >> 1)) ^ (r & 7);
        f16x4 vf = *(const f16x4*)(sV + r * 64 + c16 * 8 + (q & 1) * 4);
        O[0][nto] = __builtin_amdgcn_mfma_f32_16x16x16f16(vf, pf[0][nt], O[0][nto], 0, 0, 0);
        O[1][nto] = __builtin_amdgcn_mfma_f32_16x16x16f16(vf, pf[1][nt], O[1][nto], 0, 0, 0);
      }
    }
  }

  // ---- epilogue: l = O[grp][4][0] (d-row 64, lives in q==0 lanes), broadcast ----
  int b = bh >> 4, h = bh & 15;
#pragma unroll
  for (int grp = 0; grp < 2; ++grp) {
    float l = __shfl(O[grp][4][0], lm, 64);  // source lane lm (q==0) holds the rowsum
    float inv = 1.f / l;
    size_t token = (size_t)b * Nn + qt * 128 + wv * 32 + grp * 16 + lm;
#pragma unroll
    for (int nto = 0; nto < 4; ++nto) {
      f16x4 o4;
#pragma unroll
      for (int g = 0; g < 4; ++g) o4[g] = (f16)(O[grp][nto][g] * inv);
      *(f16x4*)(attout + token * (size_t)(Hh * DH) + h * 64 + nto * 16 + q * 4) = o4;
    }
  }
}

// ---------------- launch ----------------
extern "C" void kernel_launch(void* const* d_in, const int* in_sizes, int n_in,
                              void* d_out, int out_size, void* d_ws, size_t ws_size,
                              hipStream_t stream) {
  const float* x     = (const float*)d_in[0];
  const float* freqs = (const float*)d_in[1];
  const float* fbias = (const float*)d_in[2];
  const float* gamma = (const float*)d_in[3];
  const float* beta  = (const float*)d_in[4];
  const float* w_qk  = (const float*)d_in[5];
  const float* w_v   = (const float*)d_in[6];
  const float* w_out = (const float*)d_in[7];
  const float* b_out = (const float*)d_in[8];
  float* out = (float*)d_out;

  const size_t T = (size_t)Bb * Nn;  // 8192 tokens
  f16* WqkvT = (f16*)d_ws;                        // [3072][1024]
  f16* WoutT = WqkvT + (size_t)EQKV * DIM;        // [1024][1024]
  float2* trigQ = (float2*)(WoutT + (size_t)DIM * DIM);  // [1024*64] float2 (512 KB)
  float2* trigK = trigQ + (size_t)Nn * DH;               // [1024*64] float2 (512 KB)
  f16* Xn    = (f16*)(trigK + (size_t)Nn * DH);   // [8192][1024]
  f16* AttO  = Xn + T * DIM;                      // [8192][1024]
  f16* Qp    = AttO + T * DIM;                    // [128][1024][128]
  f16* Kp    = Qp + (size_t)128 * Nn * 128;       // [128][1024][128]
  f16* Vt    = Kp + (size_t)128 * Nn * 128;       // [128][64][1024]

  // fused prep: weight transpose (z 0-2) + trig (z 3) + LayerNorm (z 4-7)
  prep_kernel<<<dim3(64, 32, 8), 256, 0, stream>>>(
      w_qk, w_v, w_out, WqkvT, WoutT, freqs, fbias, trigQ, trigK,
      x, gamma, beta, Xn);

  // QKV projection + fused polar/V-transpose epilogue: 1536 blocks, 3/CU (r13 best)
  gemm_qkv<<<(int)(T / 128) * (EQKV / 128), 256, 0, stream>>>(
      Xn, WqkvT, Qp, Kp, Vt, trigQ, trigK, (int)T, DIM);

  // attention: v5 shell — 1024 blocks (128 bh x 8 qt) x 256 threads
  attn_kernel<<<Bb * Hh * (Nn / 128), 256, 0, stream>>>(Qp, Kp, Vt, AttO);

  // out-proj: 512 blocks (%8==0) with bijective XCD swizzle
  gemm_bt<true><<<(int)(T / 128) * (DIM / 128), 256, 0, stream>>>(
      AttO, WoutT, (void*)out, b_out, (int)T, DIM, DIM);
}